// Round 14
// baseline (71.691 us; speedup 1.0000x reference)
//
#include <hip/hip_runtime.h>

// out[b,n] = f_n(s[b,n]) where f_n is a fixed scalar function per neuron
// (softmax-gated mix of 4 activations, gates from a per-neuron 4->4->4 MLP).
// ALGORITHM: per launch, build a per-neuron 128-interval piecewise-linear
// LUT of f_n over [-8,8] (h=0.125; x=0 exactly on a knot so the relu kink
// is free; max|s| ~ 5.7 sigma << 8). Table in d_ws as adjacent pairs
// (f_i, f_{i+1}) -> main kernel = 1 coalesced x-load, ~9 VALU, one 8B
// gather (L2-resident slice), 1 lerp fma, 1 store. Collapses ~262 busy
// cy/elem (R13 measured) to ~20 -> memory-bound.
// Fallback to the R13 ALU kernel if ws_size < 4MB.

typedef float v2f __attribute__((ext_vector_type(2)));
#define SPL(x) ((v2f)(x))
#define L2E 1.44269504088896340736f

static __device__ __forceinline__ float hexp2(float x){ return __builtin_amdgcn_exp2f(x); }
static __device__ __forceinline__ float hrcp(float x){ return __builtin_amdgcn_rcpf(x); }
static __device__ __forceinline__ float sigm(float z){ return hrcp(1.0f + hexp2(-z*L2E)); }

// Exact per-neuron gate eval (R1-proven math, absmax 7.8e-3 vs ref).
static __device__ float eval_gate(float x, const float4* w1, const float4 c1,
                                  const float4* w2, const float4 c2) {
    const float a0 = fmaxf(x, 0.f), a2 = fminf(x, 0.f), a3 = x;
    const float a1 = sigm(x);
    const float h0 = sigm(fmaf(a0,w1[0].x, fmaf(a1,w1[1].x, fmaf(a2,w1[2].x, fmaf(a3,w1[3].x, c1.x)))));
    const float h1 = sigm(fmaf(a0,w1[0].y, fmaf(a1,w1[1].y, fmaf(a2,w1[2].y, fmaf(a3,w1[3].y, c1.y)))));
    const float h2 = sigm(fmaf(a0,w1[0].z, fmaf(a1,w1[1].z, fmaf(a2,w1[2].z, fmaf(a3,w1[3].z, c1.z)))));
    const float h3 = sigm(fmaf(a0,w1[0].w, fmaf(a1,w1[1].w, fmaf(a2,w1[2].w, fmaf(a3,w1[3].w, c1.w)))));
    const float l0 = fmaf(h0,w2[0].x, fmaf(h1,w2[1].x, fmaf(h2,w2[2].x, fmaf(h3,w2[3].x, c2.x))));
    const float l1 = fmaf(h0,w2[0].y, fmaf(h1,w2[1].y, fmaf(h2,w2[2].y, fmaf(h3,w2[3].y, c2.y))));
    const float l2 = fmaf(h0,w2[0].z, fmaf(h1,w2[1].z, fmaf(h2,w2[2].z, fmaf(h3,w2[3].z, c2.z))));
    const float l3 = fmaf(h0,w2[0].w, fmaf(h1,w2[1].w, fmaf(h2,w2[2].w, fmaf(h3,w2[3].w, c2.w))));
    const float e0 = hexp2(l0*L2E), e1 = hexp2(l1*L2E), e2 = hexp2(l2*L2E), e3 = hexp2(l3*L2E);
    const float den = (e0+e1)+(e2+e3);
    const float num = fmaf(e0,a0, fmaf(e1,a1, fmaf(e2,a2, e3*a3)));
    return num * hrcp(den);
}

// One wave per neuron; lane L evaluates grid points 2L, 2L+1, 2L+2 and
// stores pairs (f_i,f_{i+1}) for i=2L,2L+1 as one float4.
__global__ __launch_bounds__(256) void build_lut(
    const float* __restrict__ W1, const float* __restrict__ b1,
    const float* __restrict__ W2, const float* __restrict__ b2,
    float* __restrict__ tab, int N)
{
    const int gid  = blockIdx.x * 256 + threadIdx.x;
    const int n    = gid >> 6;
    const int lane = gid & 63;
    if (n >= N) return;
    const float4* W1v = (const float4*)W1;
    const float4* W2v = (const float4*)W2;
    float4 w1[4], w2[4];
    #pragma unroll
    for (int k = 0; k < 4; ++k) { w1[k] = W1v[(size_t)n*4 + k]; w2[k] = W2v[(size_t)n*4 + k]; }
    const float4 c1 = ((const float4*)b1)[n];
    const float4 c2 = ((const float4*)b2)[n];

    float f[3];
    #pragma unroll
    for (int t = 0; t < 3; ++t) {
        const float x = fmaf((float)(2*lane + t), 0.125f, -8.0f);  // [-8,8], 0 on-knot
        f[t] = eval_gate(x, w1, c1, w2, c2);
    }
    float4 st; st.x = f[0]; st.y = f[1]; st.z = f[1]; st.w = f[2];
    ((float4*)tab)[(size_t)n*64 + lane] = st;
}

// Main: thread owns neuron n; 16 rows/block. t = 8x+64; clamp to [0,127];
// gather pair; lerp. Clamped-out t extrapolates linearly from edge interval.
__global__ __launch_bounds__(256) void lut_mix(
    const float* __restrict__ s, const float* __restrict__ tab,
    float* __restrict__ out, int B, int N)
{
    const int n = blockIdx.x * 256 + threadIdx.x;
    const float* tn = tab + ((size_t)n << 8);           // n * 256 floats
    const int BCH = 16;
    const size_t sN = (size_t)N;
    const float* sp = s   + (size_t)(blockIdx.y * BCH) * sN + n;
    float*       op = out + (size_t)(blockIdx.y * BCH) * sN + n;

    float xv[16];
    #pragma unroll
    for (int r = 0; r < 16; ++r) xv[r] = sp[(size_t)r * sN];

    #pragma unroll
    for (int half = 0; half < 2; ++half) {
        float fr[8]; v2f pr[8];
        #pragma unroll
        for (int r = 0; r < 8; ++r) {
            const float t  = fmaf(xv[half*8 + r], 8.0f, 64.0f);
            float i_f = __builtin_amdgcn_fmed3f(floorf(t), 0.0f, 127.0f);
            fr[r] = t - i_f;
            const int i = (int)i_f;
            pr[r] = *(const v2f*)(tn + 2*i);            // aligned 8B gather
        }
        #pragma unroll
        for (int r = 0; r < 8; ++r)
            op[(size_t)(half*8 + r) * sN] = fmaf(fr[r], pr[r].y - pr[r].x, pr[r].x);
    }
}

// ---------------- fallback (R13 ALU kernel, proven 45.7us) ----------------
static __device__ __forceinline__ v2f fma2(v2f a, v2f b, v2f c) {
    return __builtin_elementwise_fma(a, b, c);
}
static __device__ __forceinline__ v2f exp2v(v2f y) {
    v2f r; r.x = hexp2(y.x); r.y = hexp2(y.y); return r;
}
static __device__ __forceinline__ v2f rcpv(v2f d) {
    v2f r; r.x = hrcp(d.x); r.y = hrcp(d.y); return r;
}

__global__ __launch_bounds__(256) void gatemix_fb(
    const float* __restrict__ s, const float* __restrict__ W1,
    const float* __restrict__ b1, const float* __restrict__ W2,
    const float* __restrict__ b2, float* __restrict__ out, int B, int N)
{
    const int n = blockIdx.x * 256 + threadIdx.x;
    const float4* W1v = (const float4*)W1;
    const float4* W2v = (const float4*)W2;
    v2f w1[4][4], bb1[4];
    #pragma unroll
    for (int k = 0; k < 4; ++k) {
        float4 rw = W1v[(size_t)n*4 + k];
        w1[k][0] = SPL(rw.x); w1[k][1] = SPL(rw.y);
        w1[k][2] = SPL(rw.z); w1[k][3] = SPL(rw.w);
    }
    { float4 rb = ((const float4*)b1)[n];
      bb1[0]=SPL(rb.x); bb1[1]=SPL(rb.y); bb1[2]=SPL(rb.z); bb1[3]=SPL(rb.w); }
    v2f w2d[4][3], bb2[3];
    #pragma unroll
    for (int j = 0; j < 4; ++j) {
        float4 rw = W2v[(size_t)n*4 + j];
        w2d[j][0] = SPL((rw.x - rw.w) * L2E);
        w2d[j][1] = SPL((rw.y - rw.w) * L2E);
        w2d[j][2] = SPL((rw.z - rw.w) * L2E);
    }
    { float4 rc = ((const float4*)b2)[n];
      bb2[0] = SPL((rc.x - rc.w) * L2E);
      bb2[1] = SPL((rc.y - rc.w) * L2E);
      bb2[2] = SPL((rc.z - rc.w) * L2E); }

    const v2f cn1 = SPL(8.0128205e-3f), cn2 = SPL(4.3706294e-5f), cn3 = SPL(2.8906051e-8f);
    const v2f cd1 = SPL(1.1538462e-1f), cd2 = SPL(1.4568765e-3f), cd3 = SPL(3.2372594e-6f);
    const v2f vQ = SPL(0.25f), vH = SPL(0.5f), vOne = SPL(1.0f);

    const size_t sN = (size_t)N;
    const float* sp = s   + (size_t)(blockIdx.y * 8) * sN + n;
    float*       op = out + (size_t)(blockIdx.y * 8) * sN + n;
    v2f xr[4];
    #pragma unroll
    for (int r = 0; r < 4; ++r) {
        xr[r].x = sp[(size_t)(2*r)   * sN];
        xr[r].y = sp[(size_t)(2*r+1) * sN];
    }
    #pragma unroll
    for (int it = 0; it < 4; ++it) {
        const v2f x = xr[it];
        v2f a0 = __builtin_elementwise_max(x, SPL(0.0f));
        v2f a2 = __builtin_elementwise_min(x, SPL(0.0f));
        v2f u  = x * x;
        v2f pn = fma2(fma2(fma2(cn3, u, cn2), u, cn1), u, vQ);
        v2f pd = fma2(fma2(fma2(cd3, u, cd2), u, cd1), u, vOne);
        v2f a1 = fma2(x * pn, rcpv(pd), vH);
        v2f qd[4], nm[4];
        #pragma unroll
        for (int j = 0; j < 4; ++j) {
            v2f zj = fma2(a0, w1[0][j], fma2(a1, w1[1][j],
                     fma2(a2, w1[2][j], fma2(x,  w1[3][j], bb1[j]))));
            v2f vv = zj * zj;
            v2f nn = fma2(fma2(fma2(cn3, vv, cn2), vv, cn1), vv, vQ);
            qd[j]  = fma2(fma2(fma2(cd3, vv, cd2), vv, cd1), vv, vOne);
            nm[j]  = zj * nn;
        }
        v2f p01 = qd[0] * qd[1], p23 = qd[2] * qd[3];
        v2f rr  = rcpv(p01 * p23);
        v2f i01 = p23 * rr, i23 = p01 * rr;
        v2f h0 = fma2(nm[0] * qd[1], i01, vH);
        v2f h1 = fma2(nm[1] * qd[0], i01, vH);
        v2f h2 = fma2(nm[2] * qd[3], i23, vH);
        v2f h3 = fma2(nm[3] * qd[2], i23, vH);
        v2f l0 = fma2(h0,w2d[0][0], fma2(h1,w2d[1][0], fma2(h2,w2d[2][0], fma2(h3,w2d[3][0], bb2[0]))));
        v2f l1 = fma2(h0,w2d[0][1], fma2(h1,w2d[1][1], fma2(h2,w2d[2][1], fma2(h3,w2d[3][1], bb2[1]))));
        v2f l2 = fma2(h0,w2d[0][2], fma2(h1,w2d[1][2], fma2(h2,w2d[2][2], fma2(h3,w2d[3][2], bb2[2]))));
        v2f e0 = exp2v(l0), e1 = exp2v(l1), e2 = exp2v(l2);
        v2f den = (e0 + e1) + (e2 + vOne);
        v2f num = fma2(e0, a0, fma2(e1, a1, fma2(e2, a2, x)));
        v2f o = num * rcpv(den);
        op[(size_t)(2*it)   * sN] = o.x;
        op[(size_t)(2*it+1) * sN] = o.y;
    }
}

extern "C" void kernel_launch(void* const* d_in, const int* in_sizes, int n_in,
                              void* d_out, int out_size, void* d_ws, size_t ws_size,
                              hipStream_t stream) {
    const float* s  = (const float*)d_in[0];
    const float* W1 = (const float*)d_in[1];
    const float* b1 = (const float*)d_in[2];
    const float* W2 = (const float*)d_in[3];
    const float* b2 = (const float*)d_in[4];
    float* out = (float*)d_out;

    const int K = 4;
    const int N = in_sizes[2] / K;       // b1 is N*K
    const int B = in_sizes[0] / N;       // s is B*N

    const size_t tab_bytes = (size_t)N * 256 * sizeof(float);   // 4 MB
    if (ws_size >= tab_bytes) {
        float* tab = (float*)d_ws;
        build_lut<<<dim3((N*64 + 255)/256), 256, 0, stream>>>(W1, b1, W2, b2, tab, N);
        dim3 grid(N / 256, B / 16);
        lut_mix<<<grid, 256, 0, stream>>>(s, tab, out, B, N);
    } else {
        dim3 grid(N / 256, B / 8);
        gatemix_fb<<<grid, 256, 0, stream>>>(s, W1, b1, W2, b2, out, B, N);
    }
}

// Round 15
// 34.219 us; speedup vs baseline: 2.0951x; 2.0951x over previous
//
#include <hip/hip_runtime.h>

// out[b,n] = f_n(s[b,n]) -- per-neuron scalar function (softmax-gated mix of
// 4 activations, gates from per-neuron 4->4->4 MLP), TABULATED.
// Stage 1 (build_lut): 128-interval piecewise-linear LUT per neuron over
// [-8,8], stored as adjacent pairs (f_i, f_{i+1}) -> one aligned 8B read/elem.
// Stage 2 (lut_mix): block = 64-neuron x 64-row tile. The 64 tables (64KB)
// are staged into LDS with coalesced loads; lane l owns neuron n0+l, so
// s/out stay perfectly coalesced and the data-dependent gather is a
// ds_read_b64 (LDS handles divergent addressing; random idx ~ 4-way banks).
// R14 proved the math (absmax 0.0156); R14's global-gather was TA-bound
// (VALUBusy 5%) -- this moves the divergence into LDS.

typedef float v2f __attribute__((ext_vector_type(2)));
#define SPL(x) ((v2f)(x))
#define L2E 1.44269504088896340736f

static __device__ __forceinline__ float hexp2(float x){ return __builtin_amdgcn_exp2f(x); }
static __device__ __forceinline__ float hrcp(float x){ return __builtin_amdgcn_rcpf(x); }
static __device__ __forceinline__ float sigm(float z){ return hrcp(1.0f + hexp2(-z*L2E)); }

// Exact per-neuron gate eval (R1-proven math).
static __device__ float eval_gate(float x, const float4* w1, const float4 c1,
                                  const float4* w2, const float4 c2) {
    const float a0 = fmaxf(x, 0.f), a2 = fminf(x, 0.f), a3 = x;
    const float a1 = sigm(x);
    const float h0 = sigm(fmaf(a0,w1[0].x, fmaf(a1,w1[1].x, fmaf(a2,w1[2].x, fmaf(a3,w1[3].x, c1.x)))));
    const float h1 = sigm(fmaf(a0,w1[0].y, fmaf(a1,w1[1].y, fmaf(a2,w1[2].y, fmaf(a3,w1[3].y, c1.y)))));
    const float h2 = sigm(fmaf(a0,w1[0].z, fmaf(a1,w1[1].z, fmaf(a2,w1[2].z, fmaf(a3,w1[3].z, c1.z)))));
    const float h3 = sigm(fmaf(a0,w1[0].w, fmaf(a1,w1[1].w, fmaf(a2,w1[2].w, fmaf(a3,w1[3].w, c1.w)))));
    const float l0 = fmaf(h0,w2[0].x, fmaf(h1,w2[1].x, fmaf(h2,w2[2].x, fmaf(h3,w2[3].x, c2.x))));
    const float l1 = fmaf(h0,w2[0].y, fmaf(h1,w2[1].y, fmaf(h2,w2[2].y, fmaf(h3,w2[3].y, c2.y))));
    const float l2 = fmaf(h0,w2[0].z, fmaf(h1,w2[1].z, fmaf(h2,w2[2].z, fmaf(h3,w2[3].z, c2.z))));
    const float l3 = fmaf(h0,w2[0].w, fmaf(h1,w2[1].w, fmaf(h2,w2[2].w, fmaf(h3,w2[3].w, c2.w))));
    const float e0 = hexp2(l0*L2E), e1 = hexp2(l1*L2E), e2 = hexp2(l2*L2E), e3 = hexp2(l3*L2E);
    const float den = (e0+e1)+(e2+e3);
    const float num = fmaf(e0,a0, fmaf(e1,a1, fmaf(e2,a2, e3*a3)));
    return num * hrcp(den);
}

// One wave per neuron; lane L evaluates grid points 2L, 2L+1, 2L+2 and
// stores pairs (f_i,f_{i+1}) for i=2L,2L+1 as one float4.
__global__ __launch_bounds__(256) void build_lut(
    const float* __restrict__ W1, const float* __restrict__ b1,
    const float* __restrict__ W2, const float* __restrict__ b2,
    float* __restrict__ tab, int N)
{
    const int gid  = blockIdx.x * 256 + threadIdx.x;
    const int n    = gid >> 6;
    const int lane = gid & 63;
    if (n >= N) return;
    const float4* W1v = (const float4*)W1;
    const float4* W2v = (const float4*)W2;
    float4 w1[4], w2[4];
    #pragma unroll
    for (int k = 0; k < 4; ++k) { w1[k] = W1v[(size_t)n*4 + k]; w2[k] = W2v[(size_t)n*4 + k]; }
    const float4 c1 = ((const float4*)b1)[n];
    const float4 c2 = ((const float4*)b2)[n];

    float f[3];
    #pragma unroll
    for (int t = 0; t < 3; ++t) {
        const float x = fmaf((float)(2*lane + t), 0.125f, -8.0f);  // [-8,8], 0 on-knot
        f[t] = eval_gate(x, w1, c1, w2, c2);
    }
    float4 st; st.x = f[0]; st.y = f[1]; st.z = f[1]; st.w = f[2];
    ((float4*)tab)[(size_t)n*64 + lane] = st;
}

// Main: block = 64 neurons x 64 rows. Tables staged in LDS (64KB).
// lane l -> neuron n0+l (coalesced s/out); warp w -> rows w*16..w*16+15.
__global__ __launch_bounds__(256) void lut_mix(
    const float* __restrict__ s, const float* __restrict__ tab,
    float* __restrict__ out, int B, int N)
{
    __shared__ float lut[64 * 256];                      // 64KB: 64 tables of pairs

    const int lane = threadIdx.x & 63;
    const int warp = threadIdx.x >> 6;
    const int n0   = blockIdx.x * 64;
    const int b0   = blockIdx.y * 64;

    // Stage 64 tables with coalesced loads (each iter: 1KB/wave).
    {
        const float* tg = tab + ((size_t)n0 << 8);       // n0 * 256
        #pragma unroll
        for (int idx = 0; idx < 64*256; idx += 256)
            lut[idx + threadIdx.x] = tg[idx + threadIdx.x];
    }
    __syncthreads();

    const size_t sN = (size_t)N;
    const float* sp = s   + (size_t)(b0 + warp*16) * sN + (n0 + lane);
    float*       op = out + (size_t)(b0 + warp*16) * sN + (n0 + lane);
    const float* tl = lut + (lane << 8);                 // this lane's table

    // 16 rows per thread; preload all (coalesced 256B/wave each).
    float xv[16];
    #pragma unroll
    for (int r = 0; r < 16; ++r) xv[r] = sp[(size_t)r * sN];

    #pragma unroll
    for (int half = 0; half < 2; ++half) {
        float fr[8]; v2f pr[8];
        #pragma unroll
        for (int r = 0; r < 8; ++r) {
            const float t  = fmaf(xv[half*8 + r], 8.0f, 64.0f);
            float i_f = __builtin_amdgcn_fmed3f(floorf(t), 0.0f, 127.0f);
            fr[r] = t - i_f;                             // linear extrapolation at edges
            const int i = (int)i_f;
            pr[r] = *(const v2f*)(tl + 2*i);             // ds_read_b64, 8B aligned
        }
        #pragma unroll
        for (int r = 0; r < 8; ++r)
            op[(size_t)(half*8 + r) * sN] = fmaf(fr[r], pr[r].y - pr[r].x, pr[r].x);
    }
}

// ---------------- fallback (R13 ALU kernel) ----------------
static __device__ __forceinline__ v2f fma2(v2f a, v2f b, v2f c) {
    return __builtin_elementwise_fma(a, b, c);
}
static __device__ __forceinline__ v2f exp2v(v2f y) {
    v2f r; r.x = hexp2(y.x); r.y = hexp2(y.y); return r;
}
static __device__ __forceinline__ v2f rcpv(v2f d) {
    v2f r; r.x = hrcp(d.x); r.y = hrcp(d.y); return r;
}

__global__ __launch_bounds__(256) void gatemix_fb(
    const float* __restrict__ s, const float* __restrict__ W1,
    const float* __restrict__ b1, const float* __restrict__ W2,
    const float* __restrict__ b2, float* __restrict__ out, int B, int N)
{
    const int n = blockIdx.x * 256 + threadIdx.x;
    const float4* W1v = (const float4*)W1;
    const float4* W2v = (const float4*)W2;
    v2f w1[4][4], bb1[4];
    #pragma unroll
    for (int k = 0; k < 4; ++k) {
        float4 rw = W1v[(size_t)n*4 + k];
        w1[k][0] = SPL(rw.x); w1[k][1] = SPL(rw.y);
        w1[k][2] = SPL(rw.z); w1[k][3] = SPL(rw.w);
    }
    { float4 rb = ((const float4*)b1)[n];
      bb1[0]=SPL(rb.x); bb1[1]=SPL(rb.y); bb1[2]=SPL(rb.z); bb1[3]=SPL(rb.w); }
    v2f w2d[4][3], bb2[3];
    #pragma unroll
    for (int j = 0; j < 4; ++j) {
        float4 rw = W2v[(size_t)n*4 + j];
        w2d[j][0] = SPL((rw.x - rw.w) * L2E);
        w2d[j][1] = SPL((rw.y - rw.w) * L2E);
        w2d[j][2] = SPL((rw.z - rw.w) * L2E);
    }
    { float4 rc = ((const float4*)b2)[n];
      bb2[0] = SPL((rc.x - rc.w) * L2E);
      bb2[1] = SPL((rc.y - rc.w) * L2E);
      bb2[2] = SPL((rc.z - rc.w) * L2E); }

    const v2f cn1 = SPL(8.0128205e-3f), cn2 = SPL(4.3706294e-5f), cn3 = SPL(2.8906051e-8f);
    const v2f cd1 = SPL(1.1538462e-1f), cd2 = SPL(1.4568765e-3f), cd3 = SPL(3.2372594e-6f);
    const v2f vQ = SPL(0.25f), vH = SPL(0.5f), vOne = SPL(1.0f);

    const size_t sN = (size_t)N;
    const float* sp = s   + (size_t)(blockIdx.y * 8) * sN + n;
    float*       op = out + (size_t)(blockIdx.y * 8) * sN + n;
    v2f xr[4];
    #pragma unroll
    for (int r = 0; r < 4; ++r) {
        xr[r].x = sp[(size_t)(2*r)   * sN];
        xr[r].y = sp[(size_t)(2*r+1) * sN];
    }
    #pragma unroll
    for (int it = 0; it < 4; ++it) {
        const v2f x = xr[it];
        v2f a0 = __builtin_elementwise_max(x, SPL(0.0f));
        v2f a2 = __builtin_elementwise_min(x, SPL(0.0f));
        v2f u  = x * x;
        v2f pn = fma2(fma2(fma2(cn3, u, cn2), u, cn1), u, vQ);
        v2f pd = fma2(fma2(fma2(cd3, u, cd2), u, cd1), u, vOne);
        v2f a1 = fma2(x * pn, rcpv(pd), vH);
        v2f qd[4], nm[4];
        #pragma unroll
        for (int j = 0; j < 4; ++j) {
            v2f zj = fma2(a0, w1[0][j], fma2(a1, w1[1][j],
                     fma2(a2, w1[2][j], fma2(x,  w1[3][j], bb1[j]))));
            v2f vv = zj * zj;
            v2f nn = fma2(fma2(fma2(cn3, vv, cn2), vv, cn1), vv, vQ);
            qd[j]  = fma2(fma2(fma2(cd3, vv, cd2), vv, cd1), vv, vOne);
            nm[j]  = zj * nn;
        }
        v2f p01 = qd[0] * qd[1], p23 = qd[2] * qd[3];
        v2f rr  = rcpv(p01 * p23);
        v2f i01 = p23 * rr, i23 = p01 * rr;
        v2f h0 = fma2(nm[0] * qd[1], i01, vH);
        v2f h1 = fma2(nm[1] * qd[0], i01, vH);
        v2f h2 = fma2(nm[2] * qd[3], i23, vH);
        v2f h3 = fma2(nm[3] * qd[2], i23, vH);
        v2f l0 = fma2(h0,w2d[0][0], fma2(h1,w2d[1][0], fma2(h2,w2d[2][0], fma2(h3,w2d[3][0], bb2[0]))));
        v2f l1 = fma2(h0,w2d[0][1], fma2(h1,w2d[1][1], fma2(h2,w2d[2][1], fma2(h3,w2d[3][1], bb2[1]))));
        v2f l2 = fma2(h0,w2d[0][2], fma2(h1,w2d[1][2], fma2(h2,w2d[2][2], fma2(h3,w2d[3][2], bb2[2]))));
        v2f e0 = exp2v(l0), e1 = exp2v(l1), e2 = exp2v(l2);
        v2f den = (e0 + e1) + (e2 + vOne);
        v2f num = fma2(e0, a0, fma2(e1, a1, fma2(e2, a2, x)));
        v2f o = num * rcpv(den);
        op[(size_t)(2*it)   * sN] = o.x;
        op[(size_t)(2*it+1) * sN] = o.y;
    }
}

extern "C" void kernel_launch(void* const* d_in, const int* in_sizes, int n_in,
                              void* d_out, int out_size, void* d_ws, size_t ws_size,
                              hipStream_t stream) {
    const float* s  = (const float*)d_in[0];
    const float* W1 = (const float*)d_in[1];
    const float* b1 = (const float*)d_in[2];
    const float* W2 = (const float*)d_in[3];
    const float* b2 = (const float*)d_in[4];
    float* out = (float*)d_out;

    const int K = 4;
    const int N = in_sizes[2] / K;       // b1 is N*K
    const int B = in_sizes[0] / N;       // s is B*N

    const size_t tab_bytes = (size_t)N * 256 * sizeof(float);   // 4 MB
    if (ws_size >= tab_bytes && (N % 64) == 0 && (B % 64) == 0) {
        float* tab = (float*)d_ws;
        build_lut<<<dim3((N*64 + 255)/256), 256, 0, stream>>>(W1, b1, W2, b2, tab, N);
        dim3 grid(N / 64, B / 64);
        lut_mix<<<grid, 256, 0, stream>>>(s, tab, out, B, N);
    } else {
        dim3 grid(N / 256, B / 8);
        gatemix_fb<<<grid, 256, 0, stream>>>(s, W1, b1, W2, b2, out, B, N);
    }
}

// Round 16
// 31.943 us; speedup vs baseline: 2.2444x; 1.0713x over previous
//
#include <hip/hip_runtime.h>

// out[b,n] = f_n(s[b,n]) -- per-neuron scalar function (softmax-gated mix of
// 4 activations, gates from per-neuron 4->4->4 MLP), TABULATED.
// build_lut: 129-knot piecewise-linear LUT per neuron over [-8,8] (h=0.125,
// x=0 on-knot), PLAIN layout (129 f32, stride 129 -> lane bases spread all
// 32 banks since 129 % 32 == 1).
// lut_mix: block = 64 neurons x 128 rows. 64 tables (33KB LDS -> 4 blocks/CU,
// twice R15's residency) staged coalesced; lane l owns neuron n0+l so s/out
// stay coalesced; per elem: ~9 VALU + one ds_read2_b32 (f_i,f_{i+1}) + lerp.
// 32 rows/thread in 4 batches of 8, depth-1 prefetch, rolled loop.
// R15 (64KB pairs, 2 blk/CU): 34.2us. Floor: 128MB @ 6.7TB/s ~ 19-20us.

typedef float v2f __attribute__((ext_vector_type(2)));
#define SPL(x) ((v2f)(x))
#define L2E 1.44269504088896340736f
#define TSTRIDE 129

static __device__ __forceinline__ float hexp2(float x){ return __builtin_amdgcn_exp2f(x); }
static __device__ __forceinline__ float hrcp(float x){ return __builtin_amdgcn_rcpf(x); }
static __device__ __forceinline__ float sigm(float z){ return hrcp(1.0f + hexp2(-z*L2E)); }

// Exact per-neuron gate eval (R1-proven math).
static __device__ float eval_gate(float x, const float4* w1, const float4 c1,
                                  const float4* w2, const float4 c2) {
    const float a0 = fmaxf(x, 0.f), a2 = fminf(x, 0.f), a3 = x;
    const float a1 = sigm(x);
    const float h0 = sigm(fmaf(a0,w1[0].x, fmaf(a1,w1[1].x, fmaf(a2,w1[2].x, fmaf(a3,w1[3].x, c1.x)))));
    const float h1 = sigm(fmaf(a0,w1[0].y, fmaf(a1,w1[1].y, fmaf(a2,w1[2].y, fmaf(a3,w1[3].y, c1.y)))));
    const float h2 = sigm(fmaf(a0,w1[0].z, fmaf(a1,w1[1].z, fmaf(a2,w1[2].z, fmaf(a3,w1[3].z, c1.z)))));
    const float h3 = sigm(fmaf(a0,w1[0].w, fmaf(a1,w1[1].w, fmaf(a2,w1[2].w, fmaf(a3,w1[3].w, c1.w)))));
    const float l0 = fmaf(h0,w2[0].x, fmaf(h1,w2[1].x, fmaf(h2,w2[2].x, fmaf(h3,w2[3].x, c2.x))));
    const float l1 = fmaf(h0,w2[0].y, fmaf(h1,w2[1].y, fmaf(h2,w2[2].y, fmaf(h3,w2[3].y, c2.y))));
    const float l2 = fmaf(h0,w2[0].z, fmaf(h1,w2[1].z, fmaf(h2,w2[2].z, fmaf(h3,w2[3].z, c2.z))));
    const float l3 = fmaf(h0,w2[0].w, fmaf(h1,w2[1].w, fmaf(h2,w2[2].w, fmaf(h3,w2[3].w, c2.w))));
    const float e0 = hexp2(l0*L2E), e1 = hexp2(l1*L2E), e2 = hexp2(l2*L2E), e3 = hexp2(l3*L2E);
    const float den = (e0+e1)+(e2+e3);
    const float num = fmaf(e0,a0, fmaf(e1,a1, fmaf(e2,a2, e3*a3)));
    return num * hrcp(den);
}

// One wave per neuron; lane l computes knots l and l+64; lane 0 adds knot 128.
__global__ __launch_bounds__(256) void build_lut(
    const float* __restrict__ W1, const float* __restrict__ b1,
    const float* __restrict__ W2, const float* __restrict__ b2,
    float* __restrict__ tab, int N)
{
    const int gid  = blockIdx.x * 256 + threadIdx.x;
    const int n    = gid >> 6;
    const int lane = gid & 63;
    if (n >= N) return;
    const float4* W1v = (const float4*)W1;
    const float4* W2v = (const float4*)W2;
    float4 w1[4], w2[4];
    #pragma unroll
    for (int k = 0; k < 4; ++k) { w1[k] = W1v[(size_t)n*4 + k]; w2[k] = W2v[(size_t)n*4 + k]; }
    const float4 c1 = ((const float4*)b1)[n];
    const float4 c2 = ((const float4*)b2)[n];

    float* tn = tab + (size_t)n * TSTRIDE;
    const float x0 = fmaf((float)lane, 0.125f, -8.0f);
    const float x1 = fmaf((float)(lane + 64), 0.125f, -8.0f);
    tn[lane]      = eval_gate(x0, w1, c1, w2, c2);
    tn[lane + 64] = eval_gate(x1, w1, c1, w2, c2);
    if (lane == 0) tn[128] = eval_gate(8.0f, w1, c1, w2, c2);
}

// Main: block = 64 neurons x 128 rows. 33KB LDS of plain tables.
__global__ __launch_bounds__(256) void lut_mix(
    const float* __restrict__ s, const float* __restrict__ tab,
    float* __restrict__ out, int B, int N)
{
    __shared__ float lut[64 * TSTRIDE];                  // 33024 B

    const int lane = threadIdx.x & 63;
    const int warp = threadIdx.x >> 6;
    const int n0   = blockIdx.x * 64;
    const int b0   = blockIdx.y * 128;

    // Stage 64 tables, coalesced (8256 floats).
    {
        const float* tg = tab + (size_t)n0 * TSTRIDE;
        for (int idx = threadIdx.x; idx < 64 * TSTRIDE; idx += 256)
            lut[idx] = tg[idx];
    }
    __syncthreads();

    const size_t sN = (size_t)N;
    const float* sp = s   + (size_t)(b0 + warp*32) * sN + (n0 + lane);
    float*       op = out + (size_t)(b0 + warp*32) * sN + (n0 + lane);
    const float* tl = lut + lane * TSTRIDE;              // this lane's table

    auto load8 = [&](int k, float (&xv)[8]) {
        #pragma unroll
        for (int r = 0; r < 8; ++r)
            xv[r] = sp[(size_t)(k*8 + r) * sN];
    };
    auto compute8 = [&](int k, const float (&xv)[8]) {
        float fr[8], f0[8], f1[8];
        #pragma unroll
        for (int r = 0; r < 8; ++r) {
            const float t  = fmaf(xv[r], 8.0f, 64.0f);
            float i_f = __builtin_amdgcn_fmed3f(floorf(t), 0.0f, 127.0f);
            fr[r] = t - i_f;                             // linear extrapolation at edges
            const int i = (int)i_f;
            f0[r] = tl[i];                               // fuses to ds_read2_b32
            f1[r] = tl[i + 1];
        }
        #pragma unroll
        for (int r = 0; r < 8; ++r)
            op[(size_t)(k*8 + r) * sN] = fmaf(fr[r], f1[r] - f0[r], f0[r]);
    };

    // 32 rows/thread: 4 batches of 8, depth-1 prefetch, rolled loop.
    float xa[8], xb[8];
    load8(0, xa);
    #pragma unroll 1
    for (int k = 0; k < 4; k += 2) {
        load8(k + 1, xb);
        compute8(k, xa);
        if (k + 2 < 4) load8(k + 2, xa);
        compute8(k + 1, xb);
    }
}

// ---------------- fallback (R13 ALU kernel) ----------------
static __device__ __forceinline__ v2f fma2(v2f a, v2f b, v2f c) {
    return __builtin_elementwise_fma(a, b, c);
}
static __device__ __forceinline__ v2f exp2v(v2f y) {
    v2f r; r.x = hexp2(y.x); r.y = hexp2(y.y); return r;
}
static __device__ __forceinline__ v2f rcpv(v2f d) {
    v2f r; r.x = hrcp(d.x); r.y = hrcp(d.y); return r;
}

__global__ __launch_bounds__(256) void gatemix_fb(
    const float* __restrict__ s, const float* __restrict__ W1,
    const float* __restrict__ b1, const float* __restrict__ W2,
    const float* __restrict__ b2, float* __restrict__ out, int B, int N)
{
    const int n = blockIdx.x * 256 + threadIdx.x;
    const float4* W1v = (const float4*)W1;
    const float4* W2v = (const float4*)W2;
    v2f w1[4][4], bb1[4];
    #pragma unroll
    for (int k = 0; k < 4; ++k) {
        float4 rw = W1v[(size_t)n*4 + k];
        w1[k][0] = SPL(rw.x); w1[k][1] = SPL(rw.y);
        w1[k][2] = SPL(rw.z); w1[k][3] = SPL(rw.w);
    }
    { float4 rb = ((const float4*)b1)[n];
      bb1[0]=SPL(rb.x); bb1[1]=SPL(rb.y); bb1[2]=SPL(rb.z); bb1[3]=SPL(rb.w); }
    v2f w2d[4][3], bb2[3];
    #pragma unroll
    for (int j = 0; j < 4; ++j) {
        float4 rw = W2v[(size_t)n*4 + j];
        w2d[j][0] = SPL((rw.x - rw.w) * L2E);
        w2d[j][1] = SPL((rw.y - rw.w) * L2E);
        w2d[j][2] = SPL((rw.z - rw.w) * L2E);
    }
    { float4 rc = ((const float4*)b2)[n];
      bb2[0] = SPL((rc.x - rc.w) * L2E);
      bb2[1] = SPL((rc.y - rc.w) * L2E);
      bb2[2] = SPL((rc.z - rc.w) * L2E); }

    const v2f cn1 = SPL(8.0128205e-3f), cn2 = SPL(4.3706294e-5f), cn3 = SPL(2.8906051e-8f);
    const v2f cd1 = SPL(1.1538462e-1f), cd2 = SPL(1.4568765e-3f), cd3 = SPL(3.2372594e-6f);
    const v2f vQ = SPL(0.25f), vH = SPL(0.5f), vOne = SPL(1.0f);

    const size_t sN = (size_t)N;
    const float* sp = s   + (size_t)(blockIdx.y * 8) * sN + n;
    float*       op = out + (size_t)(blockIdx.y * 8) * sN + n;
    v2f xr[4];
    #pragma unroll
    for (int r = 0; r < 4; ++r) {
        xr[r].x = sp[(size_t)(2*r)   * sN];
        xr[r].y = sp[(size_t)(2*r+1) * sN];
    }
    #pragma unroll
    for (int it = 0; it < 4; ++it) {
        const v2f x = xr[it];
        v2f a0 = __builtin_elementwise_max(x, SPL(0.0f));
        v2f a2 = __builtin_elementwise_min(x, SPL(0.0f));
        v2f u  = x * x;
        v2f pn = fma2(fma2(fma2(cn3, u, cn2), u, cn1), u, vQ);
        v2f pd = fma2(fma2(fma2(cd3, u, cd2), u, cd1), u, vOne);
        v2f a1 = fma2(x * pn, rcpv(pd), vH);
        v2f qd[4], nm[4];
        #pragma unroll
        for (int j = 0; j < 4; ++j) {
            v2f zj = fma2(a0, w1[0][j], fma2(a1, w1[1][j],
                     fma2(a2, w1[2][j], fma2(x,  w1[3][j], bb1[j]))));
            v2f vv = zj * zj;
            v2f nn = fma2(fma2(fma2(cn3, vv, cn2), vv, cn1), vv, vQ);
            qd[j]  = fma2(fma2(fma2(cd3, vv, cd2), vv, cd1), vv, vOne);
            nm[j]  = zj * nn;
        }
        v2f p01 = qd[0] * qd[1], p23 = qd[2] * qd[3];
        v2f rr  = rcpv(p01 * p23);
        v2f i01 = p23 * rr, i23 = p01 * rr;
        v2f h0 = fma2(nm[0] * qd[1], i01, vH);
        v2f h1 = fma2(nm[1] * qd[0], i01, vH);
        v2f h2 = fma2(nm[2] * qd[3], i23, vH);
        v2f h3 = fma2(nm[3] * qd[2], i23, vH);
        v2f l0 = fma2(h0,w2d[0][0], fma2(h1,w2d[1][0], fma2(h2,w2d[2][0], fma2(h3,w2d[3][0], bb2[0]))));
        v2f l1 = fma2(h0,w2d[0][1], fma2(h1,w2d[1][1], fma2(h2,w2d[2][1], fma2(h3,w2d[3][1], bb2[1]))));
        v2f l2 = fma2(h0,w2d[0][2], fma2(h1,w2d[1][2], fma2(h2,w2d[2][2], fma2(h3,w2d[3][2], bb2[2]))));
        v2f e0 = exp2v(l0), e1 = exp2v(l1), e2 = exp2v(l2);
        v2f den = (e0 + e1) + (e2 + vOne);
        v2f num = fma2(e0, a0, fma2(e1, a1, fma2(e2, a2, x)));
        v2f o = num * rcpv(den);
        op[(size_t)(2*it)   * sN] = o.x;
        op[(size_t)(2*it+1) * sN] = o.y;
    }
}

extern "C" void kernel_launch(void* const* d_in, const int* in_sizes, int n_in,
                              void* d_out, int out_size, void* d_ws, size_t ws_size,
                              hipStream_t stream) {
    const float* s  = (const float*)d_in[0];
    const float* W1 = (const float*)d_in[1];
    const float* b1 = (const float*)d_in[2];
    const float* W2 = (const float*)d_in[3];
    const float* b2 = (const float*)d_in[4];
    float* out = (float*)d_out;

    const int K = 4;
    const int N = in_sizes[2] / K;       // b1 is N*K
    const int B = in_sizes[0] / N;       // s is B*N

    const size_t tab_bytes = (size_t)N * TSTRIDE * sizeof(float);   // ~2.1 MB
    if (ws_size >= tab_bytes && (N % 64) == 0 && (B % 128) == 0) {
        float* tab = (float*)d_ws;
        build_lut<<<dim3((N*64 + 255)/256), 256, 0, stream>>>(W1, b1, W2, b2, tab, N);
        dim3 grid(N / 64, B / 128);
        lut_mix<<<grid, 256, 0, stream>>>(s, tab, out, B, N);
    } else {
        dim3 grid(N / 256, B / 8);
        gatemix_fb<<<grid, 256, 0, stream>>>(s, W1, b1, W2, b2, out, B, N);
    }
}